// Round 2
// baseline (1056.402 us; speedup 1.0000x reference)
//
#include <hip/hip_runtime.h>
#include <hip/hip_bf16.h>
#include <math.h>

// GraphSAGE 2-layer fused inference, f32.
//   Layer: out[r][o] = relu6( sum_j X[r][j] * W[o][j] ),  X = [self(128) | mean_neigh(128)]
// Layer1: feats = raw_features (1e6 x 128), rows = U1 = 180224, global indices.
// Layer2: feats = h1 (U1 x 128, in workspace), rows = B = 16384, local indices.

#define F    128
#define KNB  10
#define BM   32

// W [128][256] row-major  ->  WT [256][128] row-major
__global__ __launch_bounds__(256) void transpose_w(const float* __restrict__ W,
                                                   float* __restrict__ WT) {
    int e = blockIdx.x * 256 + threadIdx.x;   // 0 .. 32767
    int o = e >> 8;      // 0..127
    int j = e & 255;     // 0..255
    WT[j * F + o] = W[e];
}

__global__ __launch_bounds__(256) void sage_layer(
    const float* __restrict__ feats,     // [nsrc][128]
    const float* __restrict__ WT,        // [256][128]  (W transposed)
    const int*   __restrict__ selfIdx,   // [nrows]
    const int*   __restrict__ neighIdx,  // [nrows][10]
    float*       __restrict__ out,       // [nrows][128]
    int nrows)
{
    // Xs row stride 68 floats (272B, 16B-aligned): consecutive rows shift 4 banks.
    __shared__ float Xs[BM][68];         // current 64-col K-chunk of combined X
    __shared__ float Ws[64][132];        // WT chunk: Ws[jj][o], 528B rows, 16B-aligned
    __shared__ int   sidx[BM];
    __shared__ int   nidx[BM * KNB];     // 320

    const int t  = threadIdx.x;          // 0..255
    const int r0 = blockIdx.x * BM;

    if (t < BM)             sidx[t]       = selfIdx[r0 + t];
    if (t < BM * KNB)       nidx[t]       = neighIdx[(size_t)r0 * KNB + t];
    if (t + 256 < BM * KNB) nidx[t + 256] = neighIdx[(size_t)r0 * KNB + t + 256];

    // GEMM-phase mapping: per wave 8 row-groups x 8 col-groups -> both LDS
    // operand reads conflict-free (Xs: 8 consecutive rows, +4 banks/row;
    // Ws: 8 consecutive 16B chunks).
    const int ct = (t >> 6) * 8 + (t & 7);   // col group: owns cols ct*4 .. ct*4+3
    const int rt = (t >> 3) & 7;             // row group: owns rows rt, rt+8, rt+16, rt+24

    const int grow = t >> 4;             // gather: row (0..15), second row = +16
    const int gc4  = t & 15;             // gather: float4 slot within 64-col chunk

    float4 acc[4];
    #pragma unroll
    for (int i = 0; i < 4; ++i) acc[i] = make_float4(0.f, 0.f, 0.f, 0.f);

    for (int kk = 0; kk < 4; ++kk) {
        __syncthreads();   // covers index-load on iter 0; protects LDS reuse after

        // ---- stage WT chunk: Ws[jj][o] = WT[kk*64 + jj][o], 2048 float4s ----
        {
            const float4* src = (const float4*)(WT + (size_t)kk * 64 * F);
            #pragma unroll
            for (int it = 0; it < 8; ++it) {
                int e4 = t + it * 256;           // 0..2047, == jj*32 + o4
                int jj = e4 >> 5;
                int o4 = e4 & 31;
                *(float4*)&Ws[jj][o4 * 4] = src[e4];
            }
        }

        // ---- stage X chunk: Xs[row][c] = X[r0+row][kk*64 + c] ----
        if (kk < 2) {
            // self features: raw[sidx[row]][kk*64 + ...]
            #pragma unroll
            for (int half = 0; half < 2; ++half) {
                int row = grow + half * 16;
                const float4* src =
                    (const float4*)(feats + (size_t)sidx[row] * F + kk * 64);
                *(float4*)&Xs[row][gc4 * 4] = src[gc4];
            }
        } else {
            // mean over 10 neighbors, cols (kk-2)*64 ...
            #pragma unroll
            for (int half = 0; half < 2; ++half) {
                int row = grow + half * 16;
                float4 a = make_float4(0.f, 0.f, 0.f, 0.f);
                #pragma unroll
                for (int k = 0; k < KNB; ++k) {
                    const float4* src = (const float4*)(
                        feats + (size_t)nidx[row * KNB + k] * F + (kk - 2) * 64);
                    float4 v = src[gc4];
                    a.x += v.x; a.y += v.y; a.z += v.z; a.w += v.w;
                }
                const float inv = 1.0f / (float)KNB;
                a.x *= inv; a.y *= inv; a.z *= inv; a.w *= inv;
                if (isnan(a.x)) a.x = 0.5f;
                if (isnan(a.y)) a.y = 0.5f;
                if (isnan(a.z)) a.z = 0.5f;
                if (isnan(a.w)) a.w = 0.5f;
                *(float4*)&Xs[row][gc4 * 4] = a;
            }
        }
        __syncthreads();

        // ---- register-blocked GEMM: 4 rows x 4 cols per thread ----
        #pragma unroll
        for (int jj = 0; jj < 64; jj += 4) {
            float4 xv[4], wv[4];
            #pragma unroll
            for (int i = 0; i < 4; ++i)
                xv[i] = *(const float4*)&Xs[rt + 8 * i][jj];
            #pragma unroll
            for (int q = 0; q < 4; ++q)
                wv[q] = *(const float4*)&Ws[jj + q][ct * 4];
            #pragma unroll
            for (int i = 0; i < 4; ++i) {
                acc[i].x += xv[i].x * wv[0].x + xv[i].y * wv[1].x
                          + xv[i].z * wv[2].x + xv[i].w * wv[3].x;
                acc[i].y += xv[i].x * wv[0].y + xv[i].y * wv[1].y
                          + xv[i].z * wv[2].y + xv[i].w * wv[3].y;
                acc[i].z += xv[i].x * wv[0].z + xv[i].y * wv[1].z
                          + xv[i].z * wv[2].z + xv[i].w * wv[3].z;
                acc[i].w += xv[i].x * wv[0].w + xv[i].y * wv[1].w
                          + xv[i].z * wv[2].w + xv[i].w * wv[3].w;
            }
        }
    }

    // ---- epilogue: relu6 + coalesced float4 store ----
    #pragma unroll
    for (int i = 0; i < 4; ++i) {
        int r = r0 + rt + 8 * i;
        float4 v = acc[i];
        v.x = fminf(fmaxf(v.x, 0.f), 6.f);
        v.y = fminf(fmaxf(v.y, 0.f), 6.f);
        v.z = fminf(fmaxf(v.z, 0.f), 6.f);
        v.w = fminf(fmaxf(v.w, 0.f), 6.f);
        *(float4*)&out[(size_t)r * F + ct * 4] = v;
    }
}

extern "C" void kernel_launch(void* const* d_in, const int* in_sizes, int n_in,
                              void* d_out, int out_size, void* d_ws, size_t ws_size,
                              hipStream_t stream) {
    const float* raw = (const float*)d_in[0];
    const float* W1  = (const float*)d_in[1];
    const float* W2  = (const float*)d_in[2];
    const int*   u1  = (const int*)d_in[3];
    const int*   n1  = (const int*)d_in[4];
    const int*   s2  = (const int*)d_in[5];
    const int*   n2  = (const int*)d_in[6];
    float* out = (float*)d_out;

    const int U1n = in_sizes[3];         // 180224
    const int Bn  = in_sizes[5];         // 16384

    float* ws  = (float*)d_ws;
    float* WT1 = ws;                     // 256*128
    float* WT2 = ws + 256 * 128;         // 256*128
    float* h1  = ws + 2 * 256 * 128;     // U1 * 128  (~92 MB)

    hipLaunchKernelGGL(transpose_w, dim3(128), dim3(256), 0, stream, W1, WT1);
    hipLaunchKernelGGL(transpose_w, dim3(128), dim3(256), 0, stream, W2, WT2);

    hipLaunchKernelGGL(sage_layer, dim3(U1n / BM), dim3(256), 0, stream,
                       raw, WT1, u1, n1, h1, U1n);
    hipLaunchKernelGGL(sage_layer, dim3(Bn / BM), dim3(256), 0, stream,
                       h1, WT2, s2, n2, out, Bn);
}